// Round 13
// baseline (211.893 us; speedup 1.0000x reference)
//
#include <hip/hip_runtime.h>

#define B_ 4
#define T_ 512
#define C_ 128
#define NEG_INF_ (-1e22f)

// ---------------------------------------------------------------------------
// Kernel 1: q = x @ WQ, k = x @ WK (row-major (B*T, C)). Unchanged (fast:
// ~128 coalesced L2 loads/thread, 512 blocks x 256 thr, 2 blocks/CU).
// ---------------------------------------------------------------------------
__global__ __launch_bounds__(256) void qk_gemm(const float* __restrict__ x,
                                               const float* __restrict__ WQ,
                                               const float* __restrict__ WK,
                                               float* __restrict__ q,
                                               float* __restrict__ k) {
    __shared__ float xs[C_][4];        // [c][r] interleaved, 2 KB
    const int tid = threadIdx.x;
    const size_t rowbase = (size_t)blockIdx.x * 4 * C_;

    #pragma unroll
    for (int e = 0; e < 2; ++e) {
        int idx = e * 256 + tid;       // 0..511
        xs[idx & 127][idx >> 7] = x[rowbase + idx];
    }
    __syncthreads();

    const int m = tid >> 7;            // 0=Q 1=K (wave-uniform)
    const int d = tid & 127;
    const float* __restrict__ W = m ? WK : WQ;
    float a0 = 0.f, a1 = 0.f, a2 = 0.f, a3 = 0.f;
    #pragma unroll 8
    for (int c = 0; c < C_; ++c) {
        float w = W[c * C_ + d];                       // lanes stride-1
        float4 xv = *(const float4*)&xs[c][0];         // uniform broadcast
        a0 += xv.x * w; a1 += xv.y * w; a2 += xv.z * w; a3 += xv.w * w;
    }
    float* o = m ? k : q;
    o[rowbase + d]           = a0;
    o[rowbase + C_ + d]      = a1;
    o[rowbase + 2 * C_ + d]  = a2;
    o[rowbase + 3 * C_ + d]  = a3;
}

// ---------------------------------------------------------------------------
// Kernel 2: fused score + mask + softmax + PV — BARRIER-FREE score loop.
// r12 post-mortem: every profile (r2/r8/r11, and r12 by subtraction) shows
// this kernel latency/sync-bound (VALUBusy <= 29% always), never VALU-bound.
// The q->LDS staging was pure overhead: each thread consumes ONLY its own 2
// q rows (jA=tid, jB=tid+256). So: read q DIRECTLY global->regs, 16-d chunk
// = exactly one 64B line per thread per chunk, L2-resident, every byte used.
// Score loop now has ZERO barriers, zero q-LDS traffic; k/p broadcast from
// 2.5 KB LDS (wave-uniform, conflict-free). Manual 1-deep pipeline: prefetch
// chunk cd+1 while computing cd. LDS ~11 KB; 256-thr blocks (no VGPR cap,
// r11 lesson); grid 512 = 2 blocks/CU = 8 waves/CU.
// ---------------------------------------------------------------------------
__global__ __launch_bounds__(256) void lgcn_att(const float* __restrict__ x,
                                                const float* __restrict__ adj,
                                                const float* __restrict__ q,
                                                const float* __restrict__ k,
                                                const float* __restrict__ p,
                                                float* __restrict__ out) {
    __shared__ float ks[4][C_];          // 2 KB
    __shared__ float ps[C_];             // 0.5 KB
    __shared__ float outp[4][4][C_];     // 8 KB PV partials
    __shared__ float redm[4][4];
    __shared__ float reds[4][4];

    const int tid  = threadIdx.x;
    const int bid  = blockIdx.x;
    const int b    = bid >> 7;           // 4 b x 128 row-groups
    const int i0   = (bid & 127) << 2;   // 4 rows
    const int wv   = tid >> 6;           // 0..3
    const int lane = tid & 63;
    const int jA   = tid;                // first owned column
    const int jB   = tid + 256;          // second owned column

    // stage k rows (4 x 128 = 512 elems, 2/thread) and p
    #pragma unroll
    for (int e = 0; e < 2; ++e) {
        int idx = e * 256 + tid;
        ks[idx >> 7][idx & 127] =
            k[((size_t)b * T_ + i0 + (idx >> 7)) * C_ + (idx & 127)];
    }
    if (tid < C_) ps[tid] = p[tid];
    __syncthreads();                     // ks/ps ready; no more barriers
                                         // until softmax combine

    const float* qb    = q + (size_t)b * T_ * C_;
    const float* qrowA = qb + (size_t)jA * C_;
    const float* qrowB = qb + (size_t)jB * C_;

    float s4[4][2] = {{0.f, 0.f}, {0.f, 0.f}, {0.f, 0.f}, {0.f, 0.f}};

    // chunk registers: current (qa/qc) and prefetch (na/nc)
    float4 qa[4], qc[4];
    #pragma unroll
    for (int sl = 0; sl < 4; ++sl) {
        qa[sl] = *(const float4*)&qrowA[sl * 4];
        qc[sl] = *(const float4*)&qrowB[sl * 4];
    }

    #pragma unroll
    for (int cd = 0; cd < 8; ++cd) {
        float4 na[4], nc[4];
        if (cd < 7) {
            #pragma unroll
            for (int sl = 0; sl < 4; ++sl) {
                na[sl] = *(const float4*)&qrowA[(cd + 1) * 16 + sl * 4];
                nc[sl] = *(const float4*)&qrowB[(cd + 1) * 16 + sl * 4];
            }
        }
        #pragma unroll
        for (int dl = 0; dl < 4; ++dl) {
            float4 pv = *(const float4*)&ps[cd * 16 + dl * 4];        // bcast
            #pragma unroll
            for (int r = 0; r < 4; ++r) {
                float4 kv = *(const float4*)&ks[r][cd * 16 + dl * 4]; // bcast
                s4[r][0] += pv.x * fmaxf(qa[dl].x + kv.x, 0.f)
                          + pv.y * fmaxf(qa[dl].y + kv.y, 0.f)
                          + pv.z * fmaxf(qa[dl].z + kv.z, 0.f)
                          + pv.w * fmaxf(qa[dl].w + kv.w, 0.f);
                s4[r][1] += pv.x * fmaxf(qc[dl].x + kv.x, 0.f)
                          + pv.y * fmaxf(qc[dl].y + kv.y, 0.f)
                          + pv.z * fmaxf(qc[dl].z + kv.z, 0.f)
                          + pv.w * fmaxf(qc[dl].w + kv.w, 0.f);
            }
        }
        if (cd < 7) {
            #pragma unroll
            for (int sl = 0; sl < 4; ++sl) { qa[sl] = na[sl]; qc[sl] = nc[sl]; }
        }
    }

    // mask (exact -1e22 replacement == ref's add in fp32: masked exp -> 0)
    const float* adjb = adj + ((size_t)b * T_ + i0) * T_;
    #pragma unroll
    for (int r = 0; r < 4; ++r) {
        float aA = adjb[(size_t)r * T_ + jA];
        float aB = adjb[(size_t)r * T_ + jB];
        s4[r][0] = (aA > 0.f) ? s4[r][0] : NEG_INF_;
        s4[r][1] = (aB > 0.f) ? s4[r][1] : NEG_INF_;
    }

    // row max: wave covers its 128 j (two 64-j halves), 4-wave LDS combine
    #pragma unroll
    for (int r = 0; r < 4; ++r) {
        float mv = fmaxf(s4[r][0], s4[r][1]);
        #pragma unroll
        for (int o = 32; o > 0; o >>= 1)
            mv = fmaxf(mv, __shfl_xor(mv, o, 64));
        if (lane == 0) redm[wv][r] = mv;
    }
    __syncthreads();
    float e4[4][2];
    #pragma unroll
    for (int r = 0; r < 4; ++r) {
        float rowmax = fmaxf(fmaxf(redm[0][r], redm[1][r]),
                             fmaxf(redm[2][r], redm[3][r]));
        e4[r][0] = __expf(s4[r][0] - rowmax);
        e4[r][1] = __expf(s4[r][1] - rowmax);
        float sm = e4[r][0] + e4[r][1];
        #pragma unroll
        for (int o = 32; o > 0; o >>= 1)
            sm += __shfl_xor(sm, o, 64);
        if (lane == 0) reds[wv][r] = sm;
    }

    // PV: wave covers j in [wv*64,+64) and [256+wv*64,+64); readlane bcast;
    // lane owns d-pair {2*lane, 2*lane+1}.
    const float2* xb2 = (const float2*)(x + (size_t)b * T_ * C_);
    float2 acc[4];
    #pragma unroll
    for (int r = 0; r < 4; ++r) acc[r] = make_float2(0.f, 0.f);
    const int jbase = wv * 64;
    #pragma unroll 2
    for (int l = 0; l < 64; ++l) {
        float2 xv0 = xb2[(size_t)(jbase + l) * 64 + lane];        // coalesced
        float2 xv1 = xb2[(size_t)(256 + jbase + l) * 64 + lane];
        #pragma unroll
        for (int r = 0; r < 4; ++r) {
            float a0 = __int_as_float(
                __builtin_amdgcn_readlane(__float_as_int(e4[r][0]), l));
            float a1 = __int_as_float(
                __builtin_amdgcn_readlane(__float_as_int(e4[r][1]), l));
            acc[r].x += a0 * xv0.x + a1 * xv1.x;
            acc[r].y += a0 * xv0.y + a1 * xv1.y;
        }
    }
    #pragma unroll
    for (int r = 0; r < 4; ++r)
        *(float2*)&outp[wv][r][lane * 2] = acc[r];
    __syncthreads();                   // outp + reds visible to all

    // combine 4 waves' partials, normalize, write. 512 outputs, 2/thread.
    #pragma unroll
    for (int e = 0; e < 2; ++e) {
        const int row = (tid >> 7) + e * 2;   // 0..3
        const int d   = tid & 127;
        float v = outp[0][row][d] + outp[1][row][d]
                + outp[2][row][d] + outp[3][row][d];
        float denom = reds[0][row] + reds[1][row] + reds[2][row] + reds[3][row];
        out[((size_t)b * T_ + i0 + row) * C_ + d] = v / denom;
    }
}

extern "C" void kernel_launch(void* const* d_in, const int* in_sizes, int n_in,
                              void* d_out, int out_size, void* d_ws, size_t ws_size,
                              hipStream_t stream) {
    const float* x   = (const float*)d_in[0];
    const float* adj = (const float*)d_in[1];
    const float* WQ  = (const float*)d_in[2];
    const float* WK  = (const float*)d_in[3];
    const float* p   = (const float*)d_in[4];
    float* outp = (float*)d_out;

    float* q = (float*)d_ws;                       // 1 MB
    float* k = q + (size_t)B_ * T_ * C_;           // 1 MB
    (void)ws_size; (void)in_sizes; (void)n_in;

    qk_gemm<<<512, 256, 0, stream>>>(x, WQ, WK, q, k);
    lgcn_att<<<512, 256, 0, stream>>>(x, adj, q, k, p, outp);
}